// Round 9
// baseline (431.291 us; speedup 1.0000x reference)
//
#include <hip/hip_runtime.h>
#include <hip/hip_bf16.h>
#include <math.h>

typedef __bf16 bf16x8 __attribute__((ext_vector_type(8)));
typedef __bf16 bf16x4 __attribute__((ext_vector_type(4)));
typedef float  f32x4  __attribute__((ext_vector_type(4)));

static constexpr int kV = 4;
static constexpr int kN = 1536;
static constexpr int kD = 256;
static constexpr int kTopK = 32;

// ---- f32 -> bf16 pre-convert of H + all weights; also zeros Vmean --------
__global__ __launch_bounds__(256) void convert_kernel(
    const float* __restrict__ H, const float* __restrict__ inW,
    const float* __restrict__ outW, const float* __restrict__ WQ,
    const float* __restrict__ WK, const float* __restrict__ WV,
    __bf16* __restrict__ Hb, __bf16* __restrict__ inWb,
    __bf16* __restrict__ outWb, __bf16* __restrict__ Wqkvb,
    float* __restrict__ Vmean)
{
    if (blockIdx.x == 0) {
        f32x4 z = {0.f, 0.f, 0.f, 0.f};
        *(f32x4*)(Vmean + threadIdx.x * 4) = z;   // 256*4 = 1024 floats
    }
    int idx = (blockIdx.x * 256 + threadIdx.x) * 4;
    const float* src; __bf16* dst; int off;
    if      (idx < 1572864) { src = H;    dst = Hb;             off = idx; }
    else if (idx < 1769472) { src = inW;  dst = inWb;           off = idx - 1572864; }
    else if (idx < 1835008) { src = outW; dst = outWb;          off = idx - 1769472; }
    else if (idx < 2097152) { src = WQ;   dst = Wqkvb;          off = idx - 1835008; }
    else if (idx < 2359296) { src = WK;   dst = Wqkvb + 262144; off = idx - 2097152; }
    else                    { src = WV;   dst = Wqkvb + 524288; off = idx - 2359296; }
    f32x4 v = *(const f32x4*)(src + off);
    bf16x4 b;
#pragma unroll
    for (int j = 0; j < 4; ++j) b[j] = (__bf16)v[j];
    *(bf16x4*)(dst + off) = b;
}

// ---- qkv = Hb @ inWb^T + inB; wave tile 32x64 ----------------------------
__global__ __launch_bounds__(256) void gemm_qkv_kernel(
    const __bf16* __restrict__ A, const __bf16* __restrict__ Bm,
    const float* __restrict__ bias, __bf16* __restrict__ outB)
{
    const int Nc = 768, K = 256;
    int wave = blockIdx.x * 4 + (threadIdx.x >> 6);
    int tm  = wave / 12;
    int tn4 = wave - tm * 12;
    int lane = threadIdx.x & 63;
    int r    = lane & 15;
    int quad = lane >> 4;
    const __bf16* Ap = A + (size_t)(tm * 32 + r) * K + quad * 8;
    const __bf16* Bp = Bm + (size_t)(tn4 * 64 + r) * K + quad * 8;
    f32x4 acc[2][4] = {};
    for (int k0 = 0; k0 < K; k0 += 32) {
        bf16x8 a0 = *(const bf16x8*)(Ap + k0);
        bf16x8 a1 = *(const bf16x8*)(Ap + (size_t)16 * K + k0);
#pragma unroll
        for (int t = 0; t < 4; ++t) {
            bf16x8 b = *(const bf16x8*)(Bp + (size_t)t * 16 * K + k0);
            acc[0][t] = __builtin_amdgcn_mfma_f32_16x16x32_bf16(a0, b, acc[0][t], 0, 0, 0);
            acc[1][t] = __builtin_amdgcn_mfma_f32_16x16x32_bf16(a1, b, acc[1][t], 0, 0, 0);
        }
    }
#pragma unroll
    for (int t = 0; t < 4; ++t) {
        int gn = tn4 * 64 + t * 16 + r;
        float bv = bias[gn];
#pragma unroll
        for (int mt = 0; mt < 2; ++mt)
#pragma unroll
            for (int i = 0; i < 4; ++i) {
                int gm = tm * 32 + mt * 16 + quad * 4 + i;
                outB[(size_t)gm * Nc + gn] = (__bf16)(acc[mt][t][i] + bv);
            }
    }
}

// ---- attn (4x4 per n,h) + out-proj GEMM + alpha-blend, fused -------------
__global__ __launch_bounds__(256) void attg3_kernel(
    const __bf16* __restrict__ qkv, const __bf16* __restrict__ outWb,
    const float* __restrict__ outBias, const float* __restrict__ H,
    const float* __restrict__ alphas,
    float* __restrict__ alignedF, __bf16* __restrict__ alignedB)
{
    __shared__ __bf16 obuf[16][280];
    int n0 = blockIdx.x * 4;
    int tid = threadIdx.x;
    int h = tid >> 6, d = tid & 63;
#pragma unroll
    for (int ni = 0; ni < 4; ++ni) {
        int n = n0 + ni;
        float q[4], k[4], vv[4];
#pragma unroll
        for (int s = 0; s < 4; ++s) {
            size_t base = (size_t)(s * kN + n) * 768 + h * 64 + d;
            q[s]  = (float)qkv[base];
            k[s]  = (float)qkv[base + 256];
            vv[s] = (float)qkv[base + 512];
        }
        float att[4][4];
#pragma unroll
        for (int s = 0; s < 4; ++s)
#pragma unroll
            for (int t = 0; t < 4; ++t) {
                float p = q[s] * k[t];
#pragma unroll
                for (int off = 32; off > 0; off >>= 1) p += __shfl_xor(p, off);
                att[s][t] = p * 0.125f;
            }
#pragma unroll
        for (int s = 0; s < 4; ++s) {
            float mx = fmaxf(fmaxf(att[s][0], att[s][1]), fmaxf(att[s][2], att[s][3]));
            float e0 = __expf(att[s][0] - mx), e1 = __expf(att[s][1] - mx);
            float e2 = __expf(att[s][2] - mx), e3 = __expf(att[s][3] - mx);
            float inv = 1.f / (e0 + e1 + e2 + e3);
            float ov = (e0 * vv[0] + e1 * vv[1] + e2 * vv[2] + e3 * vv[3]) * inv;
            obuf[s * 4 + ni][h * 64 + d] = (__bf16)ov;
        }
    }
    __syncthreads();
    int w = tid >> 6, lane = tid & 63;
    int r = lane & 15, quad = lane >> 4;
    f32x4 acc[4] = {};
    for (int k0 = 0; k0 < 256; k0 += 32) {
        bf16x8 a = *(const bf16x8*)&obuf[r][quad * 8 + k0];
#pragma unroll
        for (int t = 0; t < 4; ++t) {
            bf16x8 b = *(const bf16x8*)(outWb + (size_t)(w * 64 + t * 16 + r) * 256 + quad * 8 + k0);
            acc[t] = __builtin_amdgcn_mfma_f32_16x16x32_bf16(a, b, acc[t], 0, 0, 0);
        }
    }
#pragma unroll
    for (int t = 0; t < 4; ++t) {
        int gn = w * 64 + t * 16 + r;
        float bv = outBias[gn];
#pragma unroll
        for (int i = 0; i < 4; ++i) {
            int rl = quad * 4 + i;
            int s = rl >> 2, ni = rl & 3;
            size_t gr = (size_t)(s * kN + n0 + ni);
            float a_ = alphas[s];
            size_t off = gr * kD + gn;
            float res = a_ * (acc[t][i] + bv) + (1.f - a_) * H[off];
            alignedF[off] = res;
            alignedB[off] = (__bf16)res;
        }
    }
}

// ---- stage-2 projections: Qn (bf16) / KnF,VnF (f32) + fused Vmean --------
__global__ __launch_bounds__(256) void gemm_qkv3_kernel(
    const __bf16* __restrict__ A, const __bf16* __restrict__ W,
    __bf16* __restrict__ Qn, float* __restrict__ KnF, float* __restrict__ VnF,
    float* __restrict__ Vmean)
{
    int proj = blockIdx.y;
    const __bf16* Wb = W + (size_t)proj * 4 * 65536;
    int b = blockIdx.x;
    int view = b / 48;
    int tn4 = threadIdx.x >> 6;
    int lane = threadIdx.x & 63;
    int r = lane & 15, quad = lane >> 4;
    const __bf16* Ap = A + (size_t)(b * 32 + r) * kD + quad * 8;
    const __bf16* Bp = Wb + (size_t)view * 65536 + (size_t)(tn4 * 64 + r) * kD + quad * 8;
    f32x4 acc[2][4] = {};
    for (int k0 = 0; k0 < kD; k0 += 32) {
        bf16x8 a0 = *(const bf16x8*)(Ap + k0);
        bf16x8 a1 = *(const bf16x8*)(Ap + (size_t)16 * kD + k0);
#pragma unroll
        for (int t = 0; t < 4; ++t) {
            bf16x8 bb = *(const bf16x8*)(Bp + (size_t)t * 16 * kD + k0);
            acc[0][t] = __builtin_amdgcn_mfma_f32_16x16x32_bf16(a0, bb, acc[0][t], 0, 0, 0);
            acc[1][t] = __builtin_amdgcn_mfma_f32_16x16x32_bf16(a1, bb, acc[1][t], 0, 0, 0);
        }
    }
    float* OF = (proj == 1) ? KnF : VnF;
#pragma unroll
    for (int t = 0; t < 4; ++t) {
        int gn = tn4 * 64 + t * 16 + r;
#pragma unroll
        for (int mt = 0; mt < 2; ++mt)
#pragma unroll
            for (int i = 0; i < 4; ++i) {
                int gm = b * 32 + mt * 16 + quad * 4 + i;
                if (proj == 0) Qn[(size_t)gm * kD + gn] = (__bf16)acc[mt][t][i];
                else           OF[(size_t)gm * kD + gn] = acc[mt][t][i];
            }
    }
    if (proj == 2) {
#pragma unroll
        for (int t = 0; t < 4; ++t) {
            float cs = 0.f;
#pragma unroll
            for (int mt = 0; mt < 2; ++mt)
#pragma unroll
                for (int i = 0; i < 4; ++i) cs += acc[mt][t][i];
            cs += __shfl_xor(cs, 16);
            cs += __shfl_xor(cs, 32);
            if (quad == 0)
                atomicAdd(&Vmean[view * kD + tn4 * 64 + t * 16 + r], cs * (1.f / 1536.f));
        }
    }
}

// ---- crcva: compacted topk + scores + softmax + gather + fuse ------------
__global__ __launch_bounds__(256) void crcva_kernel(
    const float* __restrict__ C,
    const __bf16* __restrict__ Qn, const float* __restrict__ KnF,
    const float* __restrict__ VnF, const float* __restrict__ Vmean,
    const float* __restrict__ alignedF, const float* __restrict__ H,
    const float* __restrict__ alpha_align, const float* __restrict__ beta,
    float* __restrict__ out)
{
    int gid = blockIdx.x;
    int j8  = gid & 7;
    int p   = j8 & 3;
    int n   = ((gid >> 3) << 1) | (j8 >> 2);
    int tid = threadIdx.x;
    int w = tid >> 6, lane = tid & 63;
    __shared__ unsigned int hist[3][257];
    __shared__ unsigned int sbin[3];
    __shared__ unsigned int idxl[3][kTopK];
    __shared__ unsigned int scnt[3];
    __shared__ unsigned int ckey[3][152];
    __shared__ unsigned int cidx[3][152];
    __shared__ float qsh[kD];
    __shared__ float wsh[96];
    __shared__ int   osh[96];
    __shared__ float part[4][kD];

    // prefetch epilogue operands (latency hidden behind topk phase)
    size_t eoff = ((size_t)p * kN + n) * kD + tid;
    float pre_al = alignedF[eoff];
    float pre_h  = H[eoff];
    float pre_vm = Vmean[p * kD + tid];
    float pre_aa = alpha_align[0];
    float pre_bt = beta[0];

    if (w < 3) {
        int q = w + (w >= p ? 1 : 0);
        const float* row = C + ((size_t)((p * kV + q) * kN + n)) * kN;
        unsigned int key[24];
#pragma unroll
        for (int j = 0; j < 6; ++j) {
            f32x4 v4 = __builtin_nontemporal_load((const f32x4*)(row + j * 256 + lane * 4));
#pragma unroll
            for (int e = 0; e < 4; ++e) {
                unsigned int u = __float_as_uint(v4[e]);
                key[j * 4 + e] = u ^ ((unsigned int)((int)u >> 31) | 0x80000000u);
            }
        }
        if (lane == 0) scnt[w] = 0;
        // candidate prefilter: value > 1.6  (key > 0xBFCCCCCD)
        const unsigned int T0 = 0xBFCCCCCDu;
        unsigned int cand = 0;
#pragma unroll
        for (int j = 0; j < 24; ++j) cand |= (key[j] > T0) ? (1u << j) : 0u;
        unsigned int myc = (unsigned int)__popc(cand);
#pragma unroll
        for (int off = 1; off < 64; off <<= 1) myc += __shfl_xor(myc, off);
        bool fastsel = (myc >= kTopK && myc <= 150);
        unsigned int pref = 0, need = kTopK, h3win = 0;
        unsigned long long below = (1ull << lane) - 1ull;
        if (fastsel) {
            // ---- ballot-compact candidates to LDS ----
            unsigned int ccnt = 0;
#pragma unroll
            for (int j = 0; j < 24; ++j) {
                bool b = (cand >> j) & 1u;
                unsigned long long m = __ballot(b);
                if (b) {
                    unsigned int pos = ccnt + (unsigned int)__popcll(m & below);
                    ckey[w][pos] = key[j];
                    cidx[w][pos] = (unsigned int)((j >> 2) * 256 + lane * 4 + (j & 3));
                }
                ccnt += (unsigned int)__popcll(m);
            }
            __builtin_amdgcn_wave_barrier();
            // ---- 4 radix passes over compacted keys (3 slots/lane) ----
#pragma unroll
            for (int pass = 0; pass < 4; ++pass) {
                const int shift = 24 - 8 * pass;
#pragma unroll
                for (int k2 = 0; k2 < 4; ++k2) hist[w][lane * 4 + k2] = 0;
                __builtin_amdgcn_wave_barrier();
#pragma unroll
                for (int s = 0; s < 3; ++s) {
                    int i = lane + s * 64;
                    if (i < (int)ccnt) {
                        unsigned int k = ckey[w][i];
                        if (pass == 0 || ((k ^ pref) >> (shift + 8)) == 0)
                            atomicAdd(&hist[w][(k >> shift) & 255u], 1u);
                    }
                }
                __builtin_amdgcn_wave_barrier();
                unsigned int h0 = hist[w][lane*4+0], h1 = hist[w][lane*4+1];
                unsigned int h2 = hist[w][lane*4+2], h3 = hist[w][lane*4+3];
                unsigned int s3 = h3, s2 = h2 + s3, s1 = h1 + s2, s0 = h0 + s1;
                unsigned int run = s0;
#pragma unroll
                for (int off = 1; off < 64; off <<= 1) {
                    unsigned int v = __shfl_down(run, off);
                    if (lane + off < 64) run += v;
                }
                unsigned int above = run - s0;
                unsigned int suf[4]  = {above+s0, above+s1, above+s2, above+s3};
                unsigned int sufN[4] = {above+s1, above+s2, above+s3, above};
#pragma unroll
                for (int k2 = 0; k2 < 4; ++k2)
                    if (suf[k2] >= need && sufN[k2] < need)
                        sbin[w] = ((unsigned int)(lane*4 + k2) << 22)
                                | ((suf[k2] - sufN[k2]) << 11) | sufN[k2];
                __builtin_amdgcn_wave_barrier();
                unsigned int pk = sbin[w];
                pref |= (pk >> 22) << shift;
                need -= (pk & 0x7FFu);
                if (pass == 3) h3win = (pk >> 11) & 0x7FFu;
                __builtin_amdgcn_wave_barrier();
            }
            unsigned int T = pref;
            if (h3win == need) {
                // fast path: take all compacted keys >= T
#pragma unroll
                for (int s = 0; s < 3; ++s) {
                    int i = lane + s * 64;
                    if (i < (int)ccnt && ckey[w][i] >= T) {
                        unsigned int pos = atomicAdd(&scnt[w], 1u);
                        idxl[w][pos] = cidx[w][i];
                    }
                }
            } else {
                // rare: jax tie rule — equals in ascending index order
                unsigned int eqBefore = 0;
                for (int j4 = 0; j4 < 6; ++j4) {
                    unsigned long long m[4];
#pragma unroll
                    for (int e = 0; e < 4; ++e)
                        m[e] = __ballot(((cand >> (j4*4+e)) & 1u) && key[j4*4+e] == T);
#pragma unroll
                    for (int e = 0; e < 4; ++e) {
                        unsigned int k = key[j4 * 4 + e];
                        bool inc = (cand >> (j4*4+e)) & 1u;
                        unsigned int rank = eqBefore;
#pragma unroll
                        for (int e2 = 0; e2 < 4; ++e2) rank += (unsigned int)__popcll(m[e2] & below);
                        for (int e2 = 0; e2 < e; ++e2) rank += (unsigned int)((m[e2] >> lane) & 1ull);
                        bool take = (inc && k > T) || (inc && k == T && rank < need);
                        if (take) {
                            unsigned int pos = atomicAdd(&scnt[w], 1u);
                            idxl[w][pos] = (unsigned int)(j4 * 256 + lane * 4 + e);
                        }
                    }
                    eqBefore += (unsigned int)(__popcll(m[0]) + __popcll(m[1])
                                             + __popcll(m[2]) + __popcll(m[3]));
                }
            }
        } else {
            // ---- fallback (never expected on N(0,1)): uncompacted exact ----
            if (myc < kTopK) {
                cand = 0;
#pragma unroll
                for (int j = 0; j < 24; ++j) cand |= (key[j] > 0x80000000u) ? (1u << j) : 0u;
            }
            need = kTopK;
#pragma unroll
            for (int pass = 0; pass < 4; ++pass) {
                const int shift = 24 - 8 * pass;
#pragma unroll
                for (int k2 = 0; k2 < 4; ++k2) hist[w][lane * 4 + k2] = 0;
                __builtin_amdgcn_wave_barrier();
#pragma unroll
                for (int j = 0; j < 24; ++j) {
                    unsigned int k = key[j];
                    bool match = ((cand >> j) & 1u) &&
                                 ((pass == 0) || (((k ^ pref) >> (shift + 8)) == 0));
                    if (match) atomicAdd(&hist[w][(k >> shift) & 255u], 1u);
                }
                __builtin_amdgcn_wave_barrier();
                unsigned int h0 = hist[w][lane*4+0], h1 = hist[w][lane*4+1];
                unsigned int h2 = hist[w][lane*4+2], h3 = hist[w][lane*4+3];
                unsigned int s3 = h3, s2 = h2 + s3, s1 = h1 + s2, s0 = h0 + s1;
                unsigned int run = s0;
#pragma unroll
                for (int off = 1; off < 64; off <<= 1) {
                    unsigned int v = __shfl_down(run, off);
                    if (lane + off < 64) run += v;
                }
                if (pass == 0) {
                    unsigned int tot = __shfl(run, 0);
                    need = need < tot ? need : tot;
                }
                unsigned int above = run - s0;
                unsigned int suf[4]  = {above+s0, above+s1, above+s2, above+s3};
                unsigned int sufN[4] = {above+s1, above+s2, above+s3, above};
#pragma unroll
                for (int k2 = 0; k2 < 4; ++k2)
                    if (suf[k2] >= need && sufN[k2] < need)
                        sbin[w] = ((unsigned int)(lane*4 + k2) << 22)
                                | ((suf[k2] - sufN[k2]) << 11) | sufN[k2];
                __builtin_amdgcn_wave_barrier();
                unsigned int pk = sbin[w];
                pref |= (pk >> 22) << shift;
                need -= (pk & 0x7FFu);
                if (pass == 3) h3win = (pk >> 11) & 0x7FFu;
                __builtin_amdgcn_wave_barrier();
            }
            unsigned int T = pref;
            if (h3win == need) {
#pragma unroll
                for (int j = 0; j < 24; ++j) {
                    if (((cand >> j) & 1u) && key[j] >= T) {
                        unsigned int pos = atomicAdd(&scnt[w], 1u);
                        idxl[w][pos] = (unsigned int)((j >> 2) * 256 + lane * 4 + (j & 3));
                    }
                }
            } else {
                unsigned int eqBefore = 0;
                for (int j4 = 0; j4 < 6; ++j4) {
                    unsigned long long m[4];
#pragma unroll
                    for (int e = 0; e < 4; ++e)
                        m[e] = __ballot(((cand >> (j4*4+e)) & 1u) && key[j4*4+e] == T);
#pragma unroll
                    for (int e = 0; e < 4; ++e) {
                        unsigned int k = key[j4 * 4 + e];
                        bool inc = (cand >> (j4*4+e)) & 1u;
                        unsigned int rank = eqBefore;
#pragma unroll
                        for (int e2 = 0; e2 < 4; ++e2) rank += (unsigned int)__popcll(m[e2] & below);
                        for (int e2 = 0; e2 < e; ++e2) rank += (unsigned int)((m[e2] >> lane) & 1ull);
                        bool take = (inc && k > T) || (inc && k == T && rank < need);
                        if (take) {
                            unsigned int pos = atomicAdd(&scnt[w], 1u);
                            idxl[w][pos] = (unsigned int)(j4 * 256 + lane * 4 + e);
                        }
                    }
                    eqBefore += (unsigned int)(__popcll(m[0]) + __popcll(m[1])
                                             + __popcll(m[2]) + __popcll(m[3]));
                }
            }
        }
    } else {
        // wave 3: stage Qn row into LDS as f32
        bf16x4 qv = *(const bf16x4*)(Qn + ((size_t)p * kN + n) * kD + lane * 4);
#pragma unroll
        for (int e = 0; e < 4; ++e) qsh[lane * 4 + e] = (float)qv[e];
    }
    __syncthreads();

    // ---- scores + per-(p,q) softmax (2 threads per candidate row) ----
    if (tid < 192) {
        int j = tid >> 1, half = tid & 1;
        int g = j >> 5, r = j & 31;
        int q = g + (g >= p ? 1 : 0);
        int cnt = (int)scnt[g];
        bool valid = (r < cnt);
        int m = valid ? (int)idxl[g][r] : 0;
        int off = valid ? (q * kN + m) * kD : 0;
        float s = 0.f;
        if (valid) {
            const float* kr = KnF + off + half * 128;
            const float* qh = qsh + half * 128;
            float a0 = 0.f, a1 = 0.f, a2 = 0.f, a3 = 0.f;
#pragma unroll
            for (int dd = 0; dd < 128; dd += 16) {
                f32x4 k0 = *(const f32x4*)(kr + dd);
                f32x4 k1 = *(const f32x4*)(kr + dd + 4);
                f32x4 k2 = *(const f32x4*)(kr + dd + 8);
                f32x4 k3 = *(const f32x4*)(kr + dd + 12);
                const float* q0 = qh + dd;
                a0 += q0[0]*k0[0] + q0[1]*k0[1] + q0[2]*k0[2] + q0[3]*k0[3];
                a1 += q0[4]*k1[0] + q0[5]*k1[1] + q0[6]*k1[2] + q0[7]*k1[3];
                a2 += q0[8]*k2[0] + q0[9]*k2[1] + q0[10]*k2[2] + q0[11]*k2[3];
                a3 += q0[12]*k3[0] + q0[13]*k3[1] + q0[14]*k3[2] + q0[15]*k3[3];
            }
            s = (a0 + a1) + (a2 + a3);
        }
        s += __shfl_xor(s, 1);
        float sc = valid ? s * 0.0625f : -1e30f;
        float mx = sc;
#pragma unroll
        for (int o2 = 2; o2 <= 32; o2 <<= 1) mx = fmaxf(mx, __shfl_xor(mx, o2));
        float e = valid ? __expf(sc - mx) : 0.f;
        float ss = e;
#pragma unroll
        for (int o2 = 2; o2 <= 32; o2 <<= 1) ss += __shfl_xor(ss, o2);
        if (half == 0) {
            wsh[j] = (ss > 0.f) ? e / ss : 0.f;
            osh[j] = off;
        }
    }
    __syncthreads();

    // ---- weighted V gather: wave w owns 24 rows, lane owns 4 dims ----
    {
        float a0 = 0.f, a1 = 0.f, a2 = 0.f, a3 = 0.f;
#pragma unroll
        for (int jj = 0; jj < 24; ++jj) {
            int j = w * 24 + jj;
            float wt = wsh[j];
            f32x4 v = *(const f32x4*)(VnF + osh[j] + lane * 4);
            a0 += wt * v[0]; a1 += wt * v[1]; a2 += wt * v[2]; a3 += wt * v[3];
        }
        f32x4 av = {a0, a1, a2, a3};
        *(f32x4*)&part[w][lane * 4] = av;
    }
    __syncthreads();

    float acc = pre_vm + part[0][tid] + part[1][tid] + part[2][tid] + part[3][tid];
    float aa = 1.f / (1.f + __expf(-pre_aa));
    float f  = fmaxf(aa * pre_al + (1.f - aa) * acc, 0.f);
    out[eoff] = pre_h * pre_bt + (1.f - pre_bt) * f;
}

extern "C" void kernel_launch(void* const* d_in, const int* in_sizes, int n_in,
                              void* d_out, int out_size, void* d_ws, size_t ws_size,
                              hipStream_t stream)
{
    const float* H        = (const float*)d_in[0];
    const float* C        = (const float*)d_in[1];
    const float* WQ       = (const float*)d_in[2];
    const float* WK       = (const float*)d_in[3];
    const float* WV       = (const float*)d_in[4];
    const float* inW      = (const float*)d_in[5];
    const float* inB      = (const float*)d_in[6];
    const float* outW     = (const float*)d_in[7];
    const float* outBias  = (const float*)d_in[8];
    const float* alphas   = (const float*)d_in[9];
    const float* alpha_al = (const float*)d_in[10];
    const float* beta     = (const float*)d_in[11];
    float* out = (float*)d_out;

    char* w = (char*)d_ws;
    __bf16* Hb       = (__bf16*)w;  w += (size_t)6144 * 256 * 2;
    __bf16* inWb     = (__bf16*)w;  w += (size_t)768 * 256 * 2;
    __bf16* outWb    = (__bf16*)w;  w += (size_t)256 * 256 * 2;
    __bf16* Wqkvb    = (__bf16*)w;  w += (size_t)3 * 4 * 256 * 256 * 2;
    __bf16* qkv      = (__bf16*)w;  w += (size_t)6144 * 768 * 2;
    __bf16* alignedB = (__bf16*)w;  w += (size_t)6144 * 256 * 2;
    float*  alignedF = (float*)w;   w += (size_t)6144 * 256 * 4;
    __bf16* Qn       = (__bf16*)w;  w += (size_t)6144 * 256 * 2;
    float*  KnF      = (float*)w;   w += (size_t)6144 * 256 * 4;
    float*  VnF      = (float*)w;   w += (size_t)6144 * 256 * 4;
    float*  Vmean    = (float*)w;   w += (size_t)4 * 256 * 4;

    // 1) pre-convert + zero Vmean
    convert_kernel<<<2560, 256, 0, stream>>>(H, inW, outW, WQ, WK, WV,
                                             Hb, inWb, outWb, Wqkvb, Vmean);
    // 2) qkv = Hb @ inWb^T + inB
    gemm_qkv_kernel<<<576, 256, 0, stream>>>(Hb, inWb, inB, qkv);
    // 3) attn + out-proj + alpha-blend (o stays in LDS)
    attg3_kernel<<<384, 256, 0, stream>>>(qkv, outWb, outBias, H, alphas,
                                          alignedF, alignedB);
    // 4) Q/K/V projections (per-view W) + fused Vmean; K,V in f32
    gemm_qkv3_kernel<<<dim3(192, 3), 256, 0, stream>>>(alignedB, Wqkvb,
                                                       Qn, KnF, VnF, Vmean);
    // 5) topk + scores + softmax + gather + final fuse (XCD-swizzled)
    crcva_kernel<<<6144, 256, 0, stream>>>(C, Qn, KnF, VnF, Vmean,
        alignedF, H, alpha_al, beta, out);
}

// Round 10
// 347.512 us; speedup vs baseline: 1.2411x; 1.2411x over previous
//
#include <hip/hip_runtime.h>
#include <hip/hip_bf16.h>
#include <math.h>

typedef __bf16 bf16x8 __attribute__((ext_vector_type(8)));
typedef __bf16 bf16x4 __attribute__((ext_vector_type(4)));
typedef float  f32x4  __attribute__((ext_vector_type(4)));

static constexpr int kV = 4;
static constexpr int kN = 1536;
static constexpr int kD = 256;
static constexpr int kTopK = 32;

// ---- f32 -> bf16 pre-convert of H + all weights; also zeros Vmean --------
__global__ __launch_bounds__(256) void convert_kernel(
    const float* __restrict__ H, const float* __restrict__ inW,
    const float* __restrict__ outW, const float* __restrict__ WQ,
    const float* __restrict__ WK, const float* __restrict__ WV,
    __bf16* __restrict__ Hb, __bf16* __restrict__ inWb,
    __bf16* __restrict__ outWb, __bf16* __restrict__ Wqkvb,
    float* __restrict__ Vmean)
{
    if (blockIdx.x == 0) {
        f32x4 z = {0.f, 0.f, 0.f, 0.f};
        *(f32x4*)(Vmean + threadIdx.x * 4) = z;   // 256*4 = 1024 floats
    }
    int idx = (blockIdx.x * 256 + threadIdx.x) * 4;
    const float* src; __bf16* dst; int off;
    if      (idx < 1572864) { src = H;    dst = Hb;             off = idx; }
    else if (idx < 1769472) { src = inW;  dst = inWb;           off = idx - 1572864; }
    else if (idx < 1835008) { src = outW; dst = outWb;          off = idx - 1769472; }
    else if (idx < 2097152) { src = WQ;   dst = Wqkvb;          off = idx - 1835008; }
    else if (idx < 2359296) { src = WK;   dst = Wqkvb + 262144; off = idx - 2097152; }
    else                    { src = WV;   dst = Wqkvb + 524288; off = idx - 2359296; }
    f32x4 v = *(const f32x4*)(src + off);
    bf16x4 b;
#pragma unroll
    for (int j = 0; j < 4; ++j) b[j] = (__bf16)v[j];
    *(bf16x4*)(dst + off) = b;
}

// ---- qkv = Hb @ inWb^T + inB; wave tile 32x64 ----------------------------
__global__ __launch_bounds__(256) void gemm_qkv_kernel(
    const __bf16* __restrict__ A, const __bf16* __restrict__ Bm,
    const float* __restrict__ bias, __bf16* __restrict__ outB)
{
    const int Nc = 768, K = 256;
    int wave = blockIdx.x * 4 + (threadIdx.x >> 6);
    int tm  = wave / 12;
    int tn4 = wave - tm * 12;
    int lane = threadIdx.x & 63;
    int r    = lane & 15;
    int quad = lane >> 4;
    const __bf16* Ap = A + (size_t)(tm * 32 + r) * K + quad * 8;
    const __bf16* Bp = Bm + (size_t)(tn4 * 64 + r) * K + quad * 8;
    f32x4 acc[2][4] = {};
    for (int k0 = 0; k0 < K; k0 += 32) {
        bf16x8 a0 = *(const bf16x8*)(Ap + k0);
        bf16x8 a1 = *(const bf16x8*)(Ap + (size_t)16 * K + k0);
#pragma unroll
        for (int t = 0; t < 4; ++t) {
            bf16x8 b = *(const bf16x8*)(Bp + (size_t)t * 16 * K + k0);
            acc[0][t] = __builtin_amdgcn_mfma_f32_16x16x32_bf16(a0, b, acc[0][t], 0, 0, 0);
            acc[1][t] = __builtin_amdgcn_mfma_f32_16x16x32_bf16(a1, b, acc[1][t], 0, 0, 0);
        }
    }
#pragma unroll
    for (int t = 0; t < 4; ++t) {
        int gn = tn4 * 64 + t * 16 + r;
        float bv = bias[gn];
#pragma unroll
        for (int mt = 0; mt < 2; ++mt)
#pragma unroll
            for (int i = 0; i < 4; ++i) {
                int gm = tm * 32 + mt * 16 + quad * 4 + i;
                outB[(size_t)gm * Nc + gn] = (__bf16)(acc[mt][t][i] + bv);
            }
    }
}

// ---- attn (4x4 per n,h) + out-proj GEMM + alpha-blend, fused -------------
__global__ __launch_bounds__(256) void attg3_kernel(
    const __bf16* __restrict__ qkv, const __bf16* __restrict__ outWb,
    const float* __restrict__ outBias, const float* __restrict__ H,
    const float* __restrict__ alphas,
    float* __restrict__ alignedF, __bf16* __restrict__ alignedB)
{
    __shared__ __bf16 obuf[16][280];
    int n0 = blockIdx.x * 4;
    int tid = threadIdx.x;
    int h = tid >> 6, d = tid & 63;
#pragma unroll
    for (int ni = 0; ni < 4; ++ni) {
        int n = n0 + ni;
        float q[4], k[4], vv[4];
#pragma unroll
        for (int s = 0; s < 4; ++s) {
            size_t base = (size_t)(s * kN + n) * 768 + h * 64 + d;
            q[s]  = (float)qkv[base];
            k[s]  = (float)qkv[base + 256];
            vv[s] = (float)qkv[base + 512];
        }
        float att[4][4];
#pragma unroll
        for (int s = 0; s < 4; ++s)
#pragma unroll
            for (int t = 0; t < 4; ++t) {
                float p = q[s] * k[t];
#pragma unroll
                for (int off = 32; off > 0; off >>= 1) p += __shfl_xor(p, off);
                att[s][t] = p * 0.125f;
            }
#pragma unroll
        for (int s = 0; s < 4; ++s) {
            float mx = fmaxf(fmaxf(att[s][0], att[s][1]), fmaxf(att[s][2], att[s][3]));
            float e0 = __expf(att[s][0] - mx), e1 = __expf(att[s][1] - mx);
            float e2 = __expf(att[s][2] - mx), e3 = __expf(att[s][3] - mx);
            float inv = 1.f / (e0 + e1 + e2 + e3);
            float ov = (e0 * vv[0] + e1 * vv[1] + e2 * vv[2] + e3 * vv[3]) * inv;
            obuf[s * 4 + ni][h * 64 + d] = (__bf16)ov;
        }
    }
    __syncthreads();
    int w = tid >> 6, lane = tid & 63;
    int r = lane & 15, quad = lane >> 4;
    f32x4 acc[4] = {};
    for (int k0 = 0; k0 < 256; k0 += 32) {
        bf16x8 a = *(const bf16x8*)&obuf[r][quad * 8 + k0];
#pragma unroll
        for (int t = 0; t < 4; ++t) {
            bf16x8 b = *(const bf16x8*)(outWb + (size_t)(w * 64 + t * 16 + r) * 256 + quad * 8 + k0);
            acc[t] = __builtin_amdgcn_mfma_f32_16x16x32_bf16(a, b, acc[t], 0, 0, 0);
        }
    }
#pragma unroll
    for (int t = 0; t < 4; ++t) {
        int gn = w * 64 + t * 16 + r;
        float bv = outBias[gn];
#pragma unroll
        for (int i = 0; i < 4; ++i) {
            int rl = quad * 4 + i;
            int s = rl >> 2, ni = rl & 3;
            size_t gr = (size_t)(s * kN + n0 + ni);
            float a_ = alphas[s];
            size_t off = gr * kD + gn;
            float res = a_ * (acc[t][i] + bv) + (1.f - a_) * H[off];
            alignedF[off] = res;
            alignedB[off] = (__bf16)res;
        }
    }
}

// ---- stage-2 Q/K/V projections (per-view W, bf16 out) + fused Vmean ------
__global__ __launch_bounds__(256) void gemm_qkv3_kernel(
    const __bf16* __restrict__ A, const __bf16* __restrict__ W,
    __bf16* __restrict__ O0, __bf16* __restrict__ O1, __bf16* __restrict__ O2,
    float* __restrict__ Vmean)
{
    int proj = blockIdx.y;
    __bf16* Ob = (proj == 0) ? O0 : (proj == 1) ? O1 : O2;
    const __bf16* Wb = W + (size_t)proj * 4 * 65536;
    int b = blockIdx.x;
    int view = b / 48;
    int tn4 = threadIdx.x >> 6;
    int lane = threadIdx.x & 63;
    int r = lane & 15, quad = lane >> 4;
    const __bf16* Ap = A + (size_t)(b * 32 + r) * kD + quad * 8;
    const __bf16* Bp = Wb + (size_t)view * 65536 + (size_t)(tn4 * 64 + r) * kD + quad * 8;
    f32x4 acc[2][4] = {};
    for (int k0 = 0; k0 < kD; k0 += 32) {
        bf16x8 a0 = *(const bf16x8*)(Ap + k0);
        bf16x8 a1 = *(const bf16x8*)(Ap + (size_t)16 * kD + k0);
#pragma unroll
        for (int t = 0; t < 4; ++t) {
            bf16x8 bb = *(const bf16x8*)(Bp + (size_t)t * 16 * kD + k0);
            acc[0][t] = __builtin_amdgcn_mfma_f32_16x16x32_bf16(a0, bb, acc[0][t], 0, 0, 0);
            acc[1][t] = __builtin_amdgcn_mfma_f32_16x16x32_bf16(a1, bb, acc[1][t], 0, 0, 0);
        }
    }
#pragma unroll
    for (int t = 0; t < 4; ++t) {
        int gn = tn4 * 64 + t * 16 + r;
#pragma unroll
        for (int mt = 0; mt < 2; ++mt)
#pragma unroll
            for (int i = 0; i < 4; ++i) {
                int gm = b * 32 + mt * 16 + quad * 4 + i;
                Ob[(size_t)gm * kD + gn] = (__bf16)acc[mt][t][i];
            }
    }
    if (proj == 2) {
#pragma unroll
        for (int t = 0; t < 4; ++t) {
            float cs = 0.f;
#pragma unroll
            for (int mt = 0; mt < 2; ++mt)
#pragma unroll
                for (int i = 0; i < 4; ++i) cs += acc[mt][t][i];
            cs += __shfl_xor(cs, 16);
            cs += __shfl_xor(cs, 32);
            if (quad == 0)
                atomicAdd(&Vmean[view * kD + tn4 * 64 + t * 16 + r], cs * (1.f / 1536.f));
        }
    }
}

// ---- crcva: compacted topk + scores + softmax + gather + fuse ------------
__global__ __launch_bounds__(256) void crcva_kernel(
    const float* __restrict__ C,
    const __bf16* __restrict__ Qn, const __bf16* __restrict__ Kn,
    const __bf16* __restrict__ Vn, const float* __restrict__ Vmean,
    const float* __restrict__ alignedF, const float* __restrict__ H,
    const float* __restrict__ alpha_align, const float* __restrict__ beta,
    float* __restrict__ out)
{
    int gid = blockIdx.x;
    int j8  = gid & 7;
    int p   = j8 & 3;
    int n   = ((gid >> 3) << 1) | (j8 >> 2);
    int tid = threadIdx.x;
    int w = tid >> 6, lane = tid & 63;
    __shared__ unsigned int hist[3][257];
    __shared__ unsigned int sbin[3];
    __shared__ unsigned int idxl[3][kTopK];
    __shared__ unsigned int scnt[3];
    __shared__ unsigned int ckey[3][152];
    __shared__ unsigned int cidx[3][152];
    __shared__ float qsh[kD];
    __shared__ float wsh[96];
    __shared__ int   osh[96];
    __shared__ float part[4][kD];

    // prefetch epilogue operands (latency hidden behind topk phase)
    size_t eoff = ((size_t)p * kN + n) * kD + tid;
    float pre_al = alignedF[eoff];
    float pre_h  = H[eoff];
    float pre_vm = Vmean[p * kD + tid];
    float pre_aa = alpha_align[0];
    float pre_bt = beta[0];

    if (w < 3) {
        int q = w + (w >= p ? 1 : 0);
        const float* row = C + ((size_t)((p * kV + q) * kN + n)) * kN;
        if (lane == 0) scnt[w] = 0;
        const unsigned int T0 = 0xBFCCCCCDu;   // transform(1.6f)
        unsigned long long below = (1ull << lane) - 1ull;
        unsigned int pref = 0, need = kTopK, h3win = 0;
        unsigned int cand, myc;
        {
            unsigned int key[24];
#pragma unroll
            for (int j = 0; j < 6; ++j) {
                f32x4 v4 = __builtin_nontemporal_load((const f32x4*)(row + j * 256 + lane * 4));
#pragma unroll
                for (int e = 0; e < 4; ++e) {
                    unsigned int u = __float_as_uint(v4[e]);
                    key[j * 4 + e] = u ^ ((unsigned int)((int)u >> 31) | 0x80000000u);
                }
            }
            cand = 0;
#pragma unroll
            for (int j = 0; j < 24; ++j) cand |= (key[j] > T0) ? (1u << j) : 0u;
            myc = (unsigned int)__popc(cand);
#pragma unroll
            for (int off = 1; off < 64; off <<= 1) myc += __shfl_xor(myc, off);
            if (myc >= kTopK && myc <= 150) {
                // ---- ballot-compact candidates to LDS; key[] dies here ----
                unsigned int ccnt = 0;
#pragma unroll
                for (int j = 0; j < 24; ++j) {
                    bool b = (cand >> j) & 1u;
                    unsigned long long m = __ballot(b);
                    if (b) {
                        unsigned int pos = ccnt + (unsigned int)__popcll(m & below);
                        ckey[w][pos] = key[j];
                        cidx[w][pos] = (unsigned int)((j >> 2) * 256 + lane * 4 + (j & 3));
                    }
                    ccnt += (unsigned int)__popcll(m);
                }
                __builtin_amdgcn_wave_barrier();
                // ---- 4 radix passes over compacted keys (3 slots/lane) ----
#pragma unroll
                for (int pass = 0; pass < 4; ++pass) {
                    const int shift = 24 - 8 * pass;
#pragma unroll
                    for (int k2 = 0; k2 < 4; ++k2) hist[w][lane * 4 + k2] = 0;
                    __builtin_amdgcn_wave_barrier();
#pragma unroll
                    for (int s = 0; s < 3; ++s) {
                        int i = lane + s * 64;
                        if (i < (int)ccnt) {
                            unsigned int k = ckey[w][i];
                            if (pass == 0 || ((k ^ pref) >> (shift + 8)) == 0)
                                atomicAdd(&hist[w][(k >> shift) & 255u], 1u);
                        }
                    }
                    __builtin_amdgcn_wave_barrier();
                    unsigned int h0 = hist[w][lane*4+0], h1 = hist[w][lane*4+1];
                    unsigned int h2 = hist[w][lane*4+2], h3 = hist[w][lane*4+3];
                    unsigned int s3 = h3, s2 = h2 + s3, s1 = h1 + s2, s0 = h0 + s1;
                    unsigned int run = s0;
#pragma unroll
                    for (int off = 1; off < 64; off <<= 1) {
                        unsigned int v = __shfl_down(run, off);
                        if (lane + off < 64) run += v;
                    }
                    unsigned int above = run - s0;
                    unsigned int suf[4]  = {above+s0, above+s1, above+s2, above+s3};
                    unsigned int sufN[4] = {above+s1, above+s2, above+s3, above};
#pragma unroll
                    for (int k2 = 0; k2 < 4; ++k2)
                        if (suf[k2] >= need && sufN[k2] < need)
                            sbin[w] = ((unsigned int)(lane*4 + k2) << 22)
                                    | ((suf[k2] - sufN[k2]) << 11) | sufN[k2];
                    __builtin_amdgcn_wave_barrier();
                    unsigned int pk = sbin[w];
                    pref |= (pk >> 22) << shift;
                    need -= (pk & 0x7FFu);
                    if (pass == 3) h3win = (pk >> 11) & 0x7FFu;
                    __builtin_amdgcn_wave_barrier();
                }
                unsigned int T = pref;
                if (h3win == need) {
                    // fast path: take all compacted keys >= T
#pragma unroll
                    for (int s = 0; s < 3; ++s) {
                        int i = lane + s * 64;
                        if (i < (int)ccnt && ckey[w][i] >= T) {
                            unsigned int pos = atomicAdd(&scnt[w], 1u);
                            idxl[w][pos] = cidx[w][i];
                        }
                    }
                } else {
                    // rare tie across boundary: reload keys; T > T0 => positive
                    unsigned int eqBefore = 0;
                    for (int j4 = 0; j4 < 6; ++j4) {
                        unsigned int k4[4];
                        f32x4 v4 = *(const f32x4*)(row + j4 * 256 + lane * 4);
#pragma unroll
                        for (int e = 0; e < 4; ++e) {
                            unsigned int u = __float_as_uint(v4[e]);
                            k4[e] = u ^ ((unsigned int)((int)u >> 31) | 0x80000000u);
                        }
                        unsigned long long m[4];
#pragma unroll
                        for (int e = 0; e < 4; ++e) m[e] = __ballot(k4[e] == T);
#pragma unroll
                        for (int e = 0; e < 4; ++e) {
                            unsigned int k = k4[e];
                            unsigned int rank = eqBefore;
#pragma unroll
                            for (int e2 = 0; e2 < 4; ++e2) rank += (unsigned int)__popcll(m[e2] & below);
                            for (int e2 = 0; e2 < e; ++e2) rank += (unsigned int)((m[e2] >> lane) & 1ull);
                            bool take = (k > T) || (k == T && rank < need);
                            if (take) {
                                unsigned int pos = atomicAdd(&scnt[w], 1u);
                                idxl[w][pos] = (unsigned int)(j4 * 256 + lane * 4 + e);
                            }
                        }
                        eqBefore += (unsigned int)(__popcll(m[0]) + __popcll(m[1])
                                                 + __popcll(m[2]) + __popcll(m[3]));
                    }
                }
            } else {
                // ---- fallback: uncompacted exact select over positives ----
                if (myc < kTopK) {
                    cand = 0;
#pragma unroll
                    for (int j = 0; j < 24; ++j) cand |= (key[j] > 0x80000000u) ? (1u << j) : 0u;
                }
#pragma unroll
                for (int pass = 0; pass < 4; ++pass) {
                    const int shift = 24 - 8 * pass;
#pragma unroll
                    for (int k2 = 0; k2 < 4; ++k2) hist[w][lane * 4 + k2] = 0;
                    __builtin_amdgcn_wave_barrier();
#pragma unroll
                    for (int j = 0; j < 24; ++j) {
                        unsigned int k = key[j];
                        bool match = ((cand >> j) & 1u) &&
                                     ((pass == 0) || (((k ^ pref) >> (shift + 8)) == 0));
                        if (match) atomicAdd(&hist[w][(k >> shift) & 255u], 1u);
                    }
                    __builtin_amdgcn_wave_barrier();
                    unsigned int h0 = hist[w][lane*4+0], h1 = hist[w][lane*4+1];
                    unsigned int h2 = hist[w][lane*4+2], h3 = hist[w][lane*4+3];
                    unsigned int s3 = h3, s2 = h2 + s3, s1 = h1 + s2, s0 = h0 + s1;
                    unsigned int run = s0;
#pragma unroll
                    for (int off = 1; off < 64; off <<= 1) {
                        unsigned int v = __shfl_down(run, off);
                        if (lane + off < 64) run += v;
                    }
                    if (pass == 0) {
                        unsigned int tot = __shfl(run, 0);
                        need = need < tot ? need : tot;
                    }
                    unsigned int above = run - s0;
                    unsigned int suf[4]  = {above+s0, above+s1, above+s2, above+s3};
                    unsigned int sufN[4] = {above+s1, above+s2, above+s3, above};
#pragma unroll
                    for (int k2 = 0; k2 < 4; ++k2)
                        if (suf[k2] >= need && sufN[k2] < need)
                            sbin[w] = ((unsigned int)(lane*4 + k2) << 22)
                                    | ((suf[k2] - sufN[k2]) << 11) | sufN[k2];
                    __builtin_amdgcn_wave_barrier();
                    unsigned int pk = sbin[w];
                    pref |= (pk >> 22) << shift;
                    need -= (pk & 0x7FFu);
                    if (pass == 3) h3win = (pk >> 11) & 0x7FFu;
                    __builtin_amdgcn_wave_barrier();
                }
                unsigned int T = pref;
                if (h3win == need) {
#pragma unroll
                    for (int j = 0; j < 24; ++j) {
                        if (((cand >> j) & 1u) && key[j] >= T) {
                            unsigned int pos = atomicAdd(&scnt[w], 1u);
                            idxl[w][pos] = (unsigned int)((j >> 2) * 256 + lane * 4 + (j & 3));
                        }
                    }
                } else {
                    unsigned int eqBefore = 0;
                    for (int j4 = 0; j4 < 6; ++j4) {
                        unsigned long long m[4];
#pragma unroll
                        for (int e = 0; e < 4; ++e)
                            m[e] = __ballot(((cand >> (j4*4+e)) & 1u) && key[j4*4+e] == T);
#pragma unroll
                        for (int e = 0; e < 4; ++e) {
                            unsigned int k = key[j4 * 4 + e];
                            bool inc = (cand >> (j4*4+e)) & 1u;
                            unsigned int rank = eqBefore;
#pragma unroll
                            for (int e2 = 0; e2 < 4; ++e2) rank += (unsigned int)__popcll(m[e2] & below);
                            for (int e2 = 0; e2 < e; ++e2) rank += (unsigned int)((m[e2] >> lane) & 1ull);
                            bool take = (inc && k > T) || (inc && k == T && rank < need);
                            if (take) {
                                unsigned int pos = atomicAdd(&scnt[w], 1u);
                                idxl[w][pos] = (unsigned int)(j4 * 256 + lane * 4 + e);
                            }
                        }
                        eqBefore += (unsigned int)(__popcll(m[0]) + __popcll(m[1])
                                                 + __popcll(m[2]) + __popcll(m[3]));
                    }
                }
            }
        }
    } else {
        // wave 3: stage Qn row into LDS as f32
        bf16x4 qv = *(const bf16x4*)(Qn + ((size_t)p * kN + n) * kD + lane * 4);
#pragma unroll
        for (int e = 0; e < 4; ++e) qsh[lane * 4 + e] = (float)qv[e];
    }
    __syncthreads();

    // ---- scores + per-(p,q) softmax (2 threads per candidate row) ----
    if (tid < 192) {
        int j = tid >> 1, half = tid & 1;
        int g = j >> 5, r = j & 31;
        int q = g + (g >= p ? 1 : 0);
        int cnt = (int)scnt[g];
        bool valid = (r < cnt);
        int m = valid ? (int)idxl[g][r] : 0;
        int off = valid ? (q * kN + m) * kD : 0;
        float s = 0.f;
        if (valid) {
            const __bf16* kr = Kn + off + half * 128;
            const float*  qh = qsh + half * 128;
            float a0 = 0.f, a1 = 0.f, a2 = 0.f, a3 = 0.f;
#pragma unroll
            for (int dd = 0; dd < 128; dd += 32) {
                bf16x8 k0 = *(const bf16x8*)(kr + dd);
                bf16x8 k1 = *(const bf16x8*)(kr + dd + 8);
                bf16x8 k2 = *(const bf16x8*)(kr + dd + 16);
                bf16x8 k3 = *(const bf16x8*)(kr + dd + 24);
                const float* q0 = qh + dd;
#pragma unroll
                for (int e = 0; e < 8; ++e) {
                    a0 += q0[e]      * (float)k0[e];
                    a1 += q0[e + 8]  * (float)k1[e];
                    a2 += q0[e + 16] * (float)k2[e];
                    a3 += q0[e + 24] * (float)k3[e];
                }
            }
            s = (a0 + a1) + (a2 + a3);
        }
        s += __shfl_xor(s, 1);
        float sc = valid ? s * 0.0625f : -1e30f;
        float mx = sc;
#pragma unroll
        for (int o2 = 2; o2 <= 32; o2 <<= 1) mx = fmaxf(mx, __shfl_xor(mx, o2));
        float e = valid ? __expf(sc - mx) : 0.f;
        float ss = e;
#pragma unroll
        for (int o2 = 2; o2 <= 32; o2 <<= 1) ss += __shfl_xor(ss, o2);
        if (half == 0) {
            wsh[j] = (ss > 0.f) ? e / ss : 0.f;
            osh[j] = off;
        }
    }
    __syncthreads();

    // ---- weighted V gather: wave w covers 24 rows, 2 rows per iter ----
    {
        int half32 = lane >> 5, l32 = lane & 31;
        float a[8] = {};
#pragma unroll
        for (int it = 0; it < 12; ++it) {
            int j = w * 24 + it * 2 + half32;
            float wt = wsh[j];
            bf16x8 v = *(const bf16x8*)(Vn + osh[j] + l32 * 8);
#pragma unroll
            for (int e = 0; e < 8; ++e) a[e] += wt * (float)v[e];
        }
#pragma unroll
        for (int e = 0; e < 8; ++e) a[e] += __shfl_xor(a[e], 32);
        if (half32 == 0) {
#pragma unroll
            for (int e = 0; e < 8; ++e) part[w][l32 * 8 + e] = a[e];
        }
    }
    __syncthreads();

    float acc = pre_vm + part[0][tid] + part[1][tid] + part[2][tid] + part[3][tid];
    float aa = 1.f / (1.f + __expf(-pre_aa));
    float f  = fmaxf(aa * pre_al + (1.f - aa) * acc, 0.f);
    out[eoff] = pre_h * pre_bt + (1.f - pre_bt) * f;
}

extern "C" void kernel_launch(void* const* d_in, const int* in_sizes, int n_in,
                              void* d_out, int out_size, void* d_ws, size_t ws_size,
                              hipStream_t stream)
{
    const float* H        = (const float*)d_in[0];
    const float* C        = (const float*)d_in[1];
    const float* WQ       = (const float*)d_in[2];
    const float* WK       = (const float*)d_in[3];
    const float* WV       = (const float*)d_in[4];
    const float* inW      = (const float*)d_in[5];
    const float* inB      = (const float*)d_in[6];
    const float* outW     = (const float*)d_in[7];
    const float* outBias  = (const float*)d_in[8];
    const float* alphas   = (const float*)d_in[9];
    const float* alpha_al = (const float*)d_in[10];
    const float* beta     = (const float*)d_in[11];
    float* out = (float*)d_out;

    char* w = (char*)d_ws;
    __bf16* Hb       = (__bf16*)w;  w += (size_t)6144 * 256 * 2;
    __bf16* inWb     = (__bf16*)w;  w += (size_t)768 * 256 * 2;
    __bf16* outWb    = (__bf16*)w;  w += (size_t)256 * 256 * 2;
    __bf16* Wqkvb    = (__bf16*)w;  w += (size_t)3 * 4 * 256 * 256 * 2;
    __bf16* qkv      = (__bf16*)w;  w += (size_t)6144 * 768 * 2;
    __bf16* alignedB = (__bf16*)w;  w += (size_t)6144 * 256 * 2;
    float*  alignedF = (float*)w;   w += (size_t)6144 * 256 * 4;
    __bf16* Qn       = (__bf16*)w;  w += (size_t)6144 * 256 * 2;
    __bf16* Kn       = (__bf16*)w;  w += (size_t)6144 * 256 * 2;
    __bf16* Vn       = (__bf16*)w;  w += (size_t)6144 * 256 * 2;
    float*  Vmean    = (float*)w;   w += (size_t)4 * 256 * 4;

    // 1) pre-convert + zero Vmean
    convert_kernel<<<2560, 256, 0, stream>>>(H, inW, outW, WQ, WK, WV,
                                             Hb, inWb, outWb, Wqkvb, Vmean);
    // 2) qkv = Hb @ inWb^T + inB
    gemm_qkv_kernel<<<576, 256, 0, stream>>>(Hb, inWb, inB, qkv);
    // 3) attn + out-proj + alpha-blend (o stays in LDS)
    attg3_kernel<<<384, 256, 0, stream>>>(qkv, outWb, outBias, H, alphas,
                                          alignedF, alignedB);
    // 4) Q/K/V projections (per-view W) + fused Vmean
    gemm_qkv3_kernel<<<dim3(192, 3), 256, 0, stream>>>(alignedB, Wqkvb,
                                                       Qn, Kn, Vn, Vmean);
    // 5) topk + scores + softmax + gather + final fuse (XCD-swizzled)
    crcva_kernel<<<6144, 256, 0, stream>>>(C, Qn, Kn, Vn, Vmean,
        alignedF, H, alpha_al, beta, out);
}